// Round 16
// baseline (50.569 us; speedup 1.0000x reference)
//
#include <hip/hip_runtime.h>
#include <hip/hip_bf16.h>
#include <math.h>

// ComplexEMA as a 5-tap block-Toeplitz convolution (single fused kernel).
//   Key identity (R16): G·W^{k-1}·V = Toeplitz(kappa) at lags 32k+t-t', so
//     Y_c = sum_{k=0..4} T_k · X_{c-k},  T_k[t][t'] = kappa(32k+t-t'),
//   with kappa(lag) = sum_n Re(gp_n q_n^lag), omega on T_0's diagonal.
//   Same k<=4 truncation as R8-R15 (|q^32|<<1), one less f16 rounding.
// One block per d (grid 1024, 512 thr); 8 waves = 8 batch rows.
//   Phase A: q_n^j table j=0..159 direct (exp/sincos), stride-17 rows.
//   Phase B: kappa[0..159]. Phase C: 10 A-frags (5 taps x 2 row-tiles)
//   overlay the table region. 3 uniform barriers, then a barrier-free
//   per-wave section: 40 MFMAs, shifted B-frags re-read from global
//   (L2-resident row; only tile 0 needs the zero mask). NO LDS, NO DS
//   ops, no pack/unpack in the wave section.
// Post-mortems: R15 occupancy moved (3->4 blocks/CU) with zero time delta
//   -> occupancy is NOT the lever; per-wave dataflow length is. R2/R11
//   never min-waves below live set. R4 sector-complete stores. R7 DS-pipe.

#define Dc 1024
#define Lc 2048

typedef _Float16 f16x8 __attribute__((ext_vector_type(8)));
typedef __fp16 h16x2 __attribute__((ext_vector_type(2)));
typedef float f32x4 __attribute__((ext_vector_type(4)));

__device__ inline f16x8 cvt8(float4 a, float4 b) {
    union { h16x2 h[4]; f16x8 v; } r;
    r.h[0] = __builtin_amdgcn_cvt_pkrtz(a.x, a.y);
    r.h[1] = __builtin_amdgcn_cvt_pkrtz(a.z, a.w);
    r.h[2] = __builtin_amdgcn_cvt_pkrtz(b.x, b.y);
    r.h[3] = __builtin_amdgcn_cvt_pkrtz(b.z, b.w);
    return r.v;
}

__global__ __launch_bounds__(512) void ema_fused(const float* __restrict__ x,
        const float* __restrict__ alpha, const float* __restrict__ delta,
        const float* __restrict__ theta, const float* __restrict__ gamma_r,
        const float* __restrict__ gamma_i, const float* __restrict__ omega,
        float* __restrict__ out) {
    // 21,760B table region (2 x 2720 floats, stride-17 rows), later
    // overlaid by 10,240B of T_k A-fragments.
    __shared__ __align__(16) char smem[2720 * 2 * 4];
    __shared__ float kap[160];
    __shared__ float gprs[16], gpis[16];

    const int tid = threadIdx.x;
    const int d = blockIdx.x;
    const int w = tid >> 6;                  // wave = batch row b
    const int l = tid & 63;
    const int g = l >> 4;
    const int m = l & 15;

    float* tr = (float*)smem;                // [jj*17 + n]
    float* ti = tr + 2720;

    // ---- issue x loads FIRST (latency hides under phases A-C)
    const size_t rowoff = ((size_t)w * Dc + d) * Lc;
    const float4* xr4 = (const float4*)(x + rowoff);
    const int base = m * 8 + 2 * g;
    float4 a0 = xr4[base],       b0 = xr4[base + 1];
    float4 a1 = xr4[base + 128], b1 = xr4[base + 129];
    float4 a2 = xr4[base + 256], b2 = xr4[base + 257];
    float4 a3 = xr4[base + 384], b3 = xr4[base + 385];

    // ---- phase A: q_n^jj table, jj=0..159 (per-thread fixed n)
    {
        int n = tid & 15;
        int idx = d * 16 + n;
        float a  = 1.f / (1.f + __expf(-alpha[idx]));
        float dl = 1.f / (1.f + __expf(-delta[idx]));
        float th = (1.f / (1.f + __expf(-theta[d]))) * (6.283185307179586f / 16.f);
        float phi = (float)(n + 1) * th;
        float radius = fminf(1.f - a * dl, 1.f);
        float lr = __logf(radius);
        for (int e = tid; e < 2560; e += 512) {
            int jj = e >> 4;                 // 0..159 (same n each iter)
            float rj = __expf((float)jj * lr);    // == reference decay
            float sn, cs; __sincosf((float)jj * phi, &sn, &cs);
            tr[jj * 17 + n] = rj * cs;
            ti[jj * 17 + n] = rj * sn;
        }
        if (tid < 16) {
            gprs[n] = gamma_r[idx] * 0.25f * a;
            gpis[n] = gamma_i[idx] * 0.25f * a;
        }
    }
    __syncthreads();

    // ---- phase B: kernel taps kappa[0..159]
    if (tid < 160) {
        float s = 0.f;
        #pragma unroll
        for (int n = 0; n < 16; ++n)
            s += gprs[n] * tr[tid * 17 + n] - gpis[n] * ti[tid * 17 + n];
        if (tid == 0) s += omega[d];
        kap[tid] = s;
    }
    __syncthreads();

    // ---- phase C: T_k A-fragments (overlay table region; reads only kap)
    _Float16* fragH = (_Float16*)smem;
    for (int s = tid; s < 640; s += 512) {
        int matk = s >> 7;                   // tap 0..4
        int sub = s & 127;
        int rt = sub >> 6, ll = sub & 63;
        int row = rt * 16 + (ll & 15);
        int kb = 8 * (ll >> 4);
        union { _Float16 h[8]; f16x8 v; } fv;
        #pragma unroll
        for (int j = 0; j < 8; ++j) {
            int lag = 32 * matk + row - kb - j;    // max 159, min -31
            fv.h[j] = (lag >= 0) ? (_Float16)kap[lag] : (_Float16)0.f;
        }
        *(f16x8*)&fragH[(matk * 128 + rt * 64 + ll) * 8] = fv.v;
    }
    __syncthreads();                     // frags visible; table dead

    // ================= per-wave independent section (no barriers) ========
    const f16x8* frag = (const f16x8*)smem;
    f16x8 tA[5][2];
    #pragma unroll
    for (int matk = 0; matk < 5; ++matk) {
        tA[matk][0] = frag[(matk * 2 + 0) * 64 + l];
        tA[matk][1] = frag[(matk * 2 + 1) * 64 + l];
    }

    f16x8 xf[4];
    xf[0] = cvt8(a0, b0); xf[1] = cvt8(a1, b1);
    xf[2] = cvt8(a2, b2); xf[3] = cvt8(a3, b3);

    float4* or4 = (float4*)(out + rowoff);

    #pragma unroll
    for (int tc = 0; tc < 4; ++tc) {
        // issue the 8 shifted loads for this tile up front (independent)
        float4 sA[4], sB[4];
        #pragma unroll
        for (int k = 1; k <= 4; ++k) {
            int chunk = tc * 16 + m - k;
            int cc = (chunk < 0) ? 0 : chunk;
            int f4i = cc * 8 + 2 * g;
            sA[k - 1] = xr4[f4i];
            sB[k - 1] = xr4[f4i + 1];
        }
        f32x4 y0 = {0.f, 0.f, 0.f, 0.f}, y1 = {0.f, 0.f, 0.f, 0.f};
        y0 = __builtin_amdgcn_mfma_f32_16x16x32_f16(tA[0][0], xf[tc], y0, 0, 0, 0);
        y1 = __builtin_amdgcn_mfma_f32_16x16x32_f16(tA[0][1], xf[tc], y1, 0, 0, 0);
        #pragma unroll
        for (int k = 1; k <= 4; ++k) {
            float4 A = sA[k - 1], B = sB[k - 1];
            if (tc == 0 && (m - k) < 0) {    // only tile 0 can underflow
                A = make_float4(0.f, 0.f, 0.f, 0.f);
                B = make_float4(0.f, 0.f, 0.f, 0.f);
            }
            f16x8 bf = cvt8(A, B);
            y0 = __builtin_amdgcn_mfma_f32_16x16x32_f16(tA[k][0], bf, y0, 0, 0, 0);
            y1 = __builtin_amdgcn_mfma_f32_16x16x32_f16(tA[k][1], bf, y1, 0, 0, 0);
        }
        float4 o0, o1;
        o0.x = y0[0]; o0.y = y0[1]; o0.z = y0[2]; o0.w = y0[3];
        o1.x = y1[0]; o1.y = y1[1]; o1.z = y1[2]; o1.w = y1[3];
        or4[(tc * 16 + m) * 8 + g]     = o0;
        or4[(tc * 16 + m) * 8 + 4 + g] = o1;
    }
}

extern "C" void kernel_launch(void* const* d_in, const int* in_sizes, int n_in,
                              void* d_out, int out_size, void* d_ws, size_t ws_size,
                              hipStream_t stream) {
    const float* x       = (const float*)d_in[0];
    const float* alpha   = (const float*)d_in[1];
    const float* delta   = (const float*)d_in[2];
    const float* theta   = (const float*)d_in[3];
    const float* gamma_r = (const float*)d_in[4];
    const float* gamma_i = (const float*)d_in[5];
    const float* omega   = (const float*)d_in[6];
    float* out = (float*)d_out;

    ema_fused<<<Dc, 512, 0, stream>>>(x, alpha, delta, theta,
                                      gamma_r, gamma_i, omega, out);
}

// Round 17
// 32.353 us; speedup vs baseline: 1.5630x; 1.5630x over previous
//
#include <hip/hip_runtime.h>
#include <hip/hip_bf16.h>
#include <math.h>

// ComplexEMA as a 5-tap block-Toeplitz convolution (single fused kernel).
//   Y_c = sum_{k=0..4} T_k · X_{c-k},  T_k[t][t'] = kappa(32k+t-t'),
//   kappa(lag) = sum_n Re(gp_n q_n^lag), omega on T_0's diagonal.
//   (identity: G·W^{k-1}·V = Toeplitz(kappa) — validated R16, same absmax)
// R17: shifted B-fragments come from LANE SHUFFLES of the already-loaded
//   xf registers, not global re-reads (R16's flaw: 32 L2 round-trips on
//   the MFMA critical path). Chunk tc*16+m-k sits in lane (g,(m-k)&15) of
//   xf[tc] (m>=k) or xf[tc-1] (m<k): one rotate per k (16 bpermute) +
//   cndmask selects. Wave section: 8 loads -> 40 MFMAs -> 8 stores.
//   No E phase, no EC LDS, no pack/unpack, no gather FMAs.
// Post-mortems: R15 occupancy not the lever; R2/R11 never clamp VGPR below
// live set; R4 sector-complete stores; R16 don't re-read shifted operands.

#define Dc 1024
#define Lc 2048

typedef _Float16 f16x8 __attribute__((ext_vector_type(8)));
typedef __fp16 h16x2 __attribute__((ext_vector_type(2)));
typedef float f32x4 __attribute__((ext_vector_type(4)));

__device__ inline f16x8 cvt8(float4 a, float4 b) {
    union { h16x2 h[4]; f16x8 v; } r;
    r.h[0] = __builtin_amdgcn_cvt_pkrtz(a.x, a.y);
    r.h[1] = __builtin_amdgcn_cvt_pkrtz(a.z, a.w);
    r.h[2] = __builtin_amdgcn_cvt_pkrtz(b.x, b.y);
    r.h[3] = __builtin_amdgcn_cvt_pkrtz(b.z, b.w);
    return r.v;
}

__device__ inline f16x8 shfl8(f16x8 v, int sl) {
    union { f16x8 f; int i[4]; } u; u.f = v;
    #pragma unroll
    for (int t = 0; t < 4; ++t) u.i[t] = __shfl(u.i[t], sl, 64);
    return u.f;
}

__device__ inline f16x8 sel8(bool c, f16x8 a, f16x8 b) {
    union { f16x8 f; int i[4]; } ua, ub, r; ua.f = a; ub.f = b;
    #pragma unroll
    for (int t = 0; t < 4; ++t) r.i[t] = c ? ua.i[t] : ub.i[t];
    return r.f;
}

__global__ __launch_bounds__(512) void ema_fused(const float* __restrict__ x,
        const float* __restrict__ alpha, const float* __restrict__ delta,
        const float* __restrict__ theta, const float* __restrict__ gamma_r,
        const float* __restrict__ gamma_i, const float* __restrict__ omega,
        float* __restrict__ out) {
    // 21,760B table region (2 x 2720 floats, stride-17 rows), later
    // overlaid by 10,240B of T_k A-fragments.
    __shared__ __align__(16) char smem[2720 * 2 * 4];
    __shared__ float kap[160];
    __shared__ float gprs[16], gpis[16];

    const int tid = threadIdx.x;
    const int d = blockIdx.x;
    const int w = tid >> 6;                  // wave = batch row b
    const int l = tid & 63;
    const int g = l >> 4;
    const int m = l & 15;

    float* tr = (float*)smem;                // [jj*17 + n]
    float* ti = tr + 2720;

    // ---- issue x loads FIRST (latency hides under phases A-C)
    const size_t rowoff = ((size_t)w * Dc + d) * Lc;
    const float4* xr4 = (const float4*)(x + rowoff);
    const int base = m * 8 + 2 * g;
    float4 a0 = xr4[base],       b0 = xr4[base + 1];
    float4 a1 = xr4[base + 128], b1 = xr4[base + 129];
    float4 a2 = xr4[base + 256], b2 = xr4[base + 257];
    float4 a3 = xr4[base + 384], b3 = xr4[base + 385];

    // ---- phase A: q_n^jj table, jj=0..159 (per-thread fixed n)
    {
        int n = tid & 15;
        int idx = d * 16 + n;
        float a  = 1.f / (1.f + __expf(-alpha[idx]));
        float dl = 1.f / (1.f + __expf(-delta[idx]));
        float th = (1.f / (1.f + __expf(-theta[d]))) * (6.283185307179586f / 16.f);
        float phi = (float)(n + 1) * th;
        float radius = fminf(1.f - a * dl, 1.f);
        float lr = __logf(radius);
        for (int e = tid; e < 2560; e += 512) {
            int jj = e >> 4;                 // 0..159 (same n each iter)
            float rj = __expf((float)jj * lr);    // == reference decay
            float sn, cs; __sincosf((float)jj * phi, &sn, &cs);
            tr[jj * 17 + n] = rj * cs;
            ti[jj * 17 + n] = rj * sn;
        }
        if (tid < 16) {
            gprs[n] = gamma_r[idx] * 0.25f * a;
            gpis[n] = gamma_i[idx] * 0.25f * a;
        }
    }
    __syncthreads();

    // ---- phase B: kernel taps kappa[0..159]
    if (tid < 160) {
        float s = 0.f;
        #pragma unroll
        for (int n = 0; n < 16; ++n)
            s += gprs[n] * tr[tid * 17 + n] - gpis[n] * ti[tid * 17 + n];
        if (tid == 0) s += omega[d];
        kap[tid] = s;
    }
    __syncthreads();

    // ---- phase C: T_k A-fragments (overlay table region; reads only kap)
    _Float16* fragH = (_Float16*)smem;
    for (int s = tid; s < 640; s += 512) {
        int matk = s >> 7;                   // tap 0..4
        int sub = s & 127;
        int rt = sub >> 6, ll = sub & 63;
        int row = rt * 16 + (ll & 15);
        int kb = 8 * (ll >> 4);
        union { _Float16 h[8]; f16x8 v; } fv;
        #pragma unroll
        for (int j = 0; j < 8; ++j) {
            int lag = 32 * matk + row - kb - j;    // max 159, min -31
            fv.h[j] = (lag >= 0) ? (_Float16)kap[lag] : (_Float16)0.f;
        }
        *(f16x8*)&fragH[(matk * 128 + rt * 64 + ll) * 8] = fv.v;
    }
    __syncthreads();                     // frags visible; table dead

    // ================= per-wave independent section (no barriers) ========
    const f16x8* frag = (const f16x8*)smem;

    f16x8 xf[4];
    xf[0] = cvt8(a0, b0); xf[1] = cvt8(a1, b1);
    xf[2] = cvt8(a2, b2); xf[3] = cvt8(a3, b3);

    f32x4 y[4][2];
    #pragma unroll
    for (int tc = 0; tc < 4; ++tc) {
        y[tc][0] = (f32x4){0.f, 0.f, 0.f, 0.f};
        y[tc][1] = (f32x4){0.f, 0.f, 0.f, 0.f};
    }

    // tap 0 (unshifted)
    {
        f16x8 t0 = frag[l], t1 = frag[64 + l];
        #pragma unroll
        for (int tc = 0; tc < 4; ++tc) {
            y[tc][0] = __builtin_amdgcn_mfma_f32_16x16x32_f16(t0, xf[tc], y[tc][0], 0, 0, 0);
            y[tc][1] = __builtin_amdgcn_mfma_f32_16x16x32_f16(t1, xf[tc], y[tc][1], 0, 0, 0);
        }
    }

    // taps 1..4: rotate xf within 16-lane m-groups, select across tiles
    const f16x8 z8 = (f16x8)(_Float16)0.f;
    #pragma unroll
    for (int k = 1; k <= 4; ++k) {
        f16x8 tk0 = frag[(2 * k) * 64 + l], tk1 = frag[(2 * k + 1) * 64 + l];
        int sl = (l & 48) | ((l - k) & 15);
        f16x8 r0 = shfl8(xf[0], sl);
        f16x8 r1 = shfl8(xf[1], sl);
        f16x8 r2 = shfl8(xf[2], sl);
        f16x8 r3 = shfl8(xf[3], sl);
        bool hi = (m >= k);
        f16x8 bf0 = sel8(hi, r0, z8);
        f16x8 bf1 = sel8(hi, r1, r0);
        f16x8 bf2 = sel8(hi, r2, r1);
        f16x8 bf3 = sel8(hi, r3, r2);
        y[0][0] = __builtin_amdgcn_mfma_f32_16x16x32_f16(tk0, bf0, y[0][0], 0, 0, 0);
        y[0][1] = __builtin_amdgcn_mfma_f32_16x16x32_f16(tk1, bf0, y[0][1], 0, 0, 0);
        y[1][0] = __builtin_amdgcn_mfma_f32_16x16x32_f16(tk0, bf1, y[1][0], 0, 0, 0);
        y[1][1] = __builtin_amdgcn_mfma_f32_16x16x32_f16(tk1, bf1, y[1][1], 0, 0, 0);
        y[2][0] = __builtin_amdgcn_mfma_f32_16x16x32_f16(tk0, bf2, y[2][0], 0, 0, 0);
        y[2][1] = __builtin_amdgcn_mfma_f32_16x16x32_f16(tk1, bf2, y[2][1], 0, 0, 0);
        y[3][0] = __builtin_amdgcn_mfma_f32_16x16x32_f16(tk0, bf3, y[3][0], 0, 0, 0);
        y[3][1] = __builtin_amdgcn_mfma_f32_16x16x32_f16(tk1, bf3, y[3][1], 0, 0, 0);
    }

    // ---- sector-dense stores
    float4* or4 = (float4*)(out + rowoff);
    #pragma unroll
    for (int tc = 0; tc < 4; ++tc) {
        float4 o0, o1;
        o0.x = y[tc][0][0]; o0.y = y[tc][0][1]; o0.z = y[tc][0][2]; o0.w = y[tc][0][3];
        o1.x = y[tc][1][0]; o1.y = y[tc][1][1]; o1.z = y[tc][1][2]; o1.w = y[tc][1][3];
        or4[(tc * 16 + m) * 8 + g]     = o0;
        or4[(tc * 16 + m) * 8 + 4 + g] = o1;
    }
}

extern "C" void kernel_launch(void* const* d_in, const int* in_sizes, int n_in,
                              void* d_out, int out_size, void* d_ws, size_t ws_size,
                              hipStream_t stream) {
    const float* x       = (const float*)d_in[0];
    const float* alpha   = (const float*)d_in[1];
    const float* delta   = (const float*)d_in[2];
    const float* theta   = (const float*)d_in[3];
    const float* gamma_r = (const float*)d_in[4];
    const float* gamma_i = (const float*)d_in[5];
    const float* omega   = (const float*)d_in[6];
    float* out = (float*)d_out;

    ema_fused<<<Dc, 512, 0, stream>>>(x, alpha, delta, theta,
                                      gamma_r, gamma_i, omega, out);
}

// Round 18
// 31.615 us; speedup vs baseline: 1.5995x; 1.0233x over previous
//
#include <hip/hip_runtime.h>
#include <hip/hip_bf16.h>
#include <math.h>

// ComplexEMA as a 5-tap block-Toeplitz convolution (single fused kernel).
//   Y_c = sum_{k=0..4} T_k · X_{c-k},  T_k[t][t'] = kappa(32k+t-t'),
//   kappa(lag) = sum_n Re(gp_n q_n^lag), omega on T_0's diagonal.
// R18: STREAMING wave section — tiles outer, store y[tc] right after its
//   10 MFMAs, rolling prev_k = rot_k(xf[tc-1]). Chip-wide this overlaps
//   the read burst with the write burst (R14/R17's all-loads-then-all-
//   stores serialized ~64MB read phase then ~64MB write phase; all four
//   prior structures converged to ~31us because of it).
// Post-mortems: R15 occupancy not the lever; R16 never re-read shifted
// operands from global; R2/R11 never clamp VGPR below live set; R4
// sector-complete stores.

#define Dc 1024
#define Lc 2048

typedef _Float16 f16x8 __attribute__((ext_vector_type(8)));
typedef __fp16 h16x2 __attribute__((ext_vector_type(2)));
typedef float f32x4 __attribute__((ext_vector_type(4)));

__device__ inline f16x8 cvt8(float4 a, float4 b) {
    union { h16x2 h[4]; f16x8 v; } r;
    r.h[0] = __builtin_amdgcn_cvt_pkrtz(a.x, a.y);
    r.h[1] = __builtin_amdgcn_cvt_pkrtz(a.z, a.w);
    r.h[2] = __builtin_amdgcn_cvt_pkrtz(b.x, b.y);
    r.h[3] = __builtin_amdgcn_cvt_pkrtz(b.z, b.w);
    return r.v;
}

__device__ inline f16x8 shfl8(f16x8 v, int sl) {
    union { f16x8 f; int i[4]; } u; u.f = v;
    #pragma unroll
    for (int t = 0; t < 4; ++t) u.i[t] = __shfl(u.i[t], sl, 64);
    return u.f;
}

__device__ inline f16x8 sel8(bool c, f16x8 a, f16x8 b) {
    union { f16x8 f; int i[4]; } ua, ub, r; ua.f = a; ub.f = b;
    #pragma unroll
    for (int t = 0; t < 4; ++t) r.i[t] = c ? ua.i[t] : ub.i[t];
    return r.f;
}

__global__ __launch_bounds__(512) void ema_fused(const float* __restrict__ x,
        const float* __restrict__ alpha, const float* __restrict__ delta,
        const float* __restrict__ theta, const float* __restrict__ gamma_r,
        const float* __restrict__ gamma_i, const float* __restrict__ omega,
        float* __restrict__ out) {
    // 21,760B table region (2 x 2720 floats, stride-17 rows), later
    // overlaid by 10,240B of T_k A-fragments.
    __shared__ __align__(16) char smem[2720 * 2 * 4];
    __shared__ float kap[160];
    __shared__ float gprs[16], gpis[16];

    const int tid = threadIdx.x;
    const int d = blockIdx.x;
    const int w = tid >> 6;                  // wave = batch row b
    const int l = tid & 63;
    const int g = l >> 4;
    const int m = l & 15;

    float* tr = (float*)smem;                // [jj*17 + n]
    float* ti = tr + 2720;

    // ---- issue x loads FIRST (latency hides under phases A-C)
    const size_t rowoff = ((size_t)w * Dc + d) * Lc;
    const float4* xr4 = (const float4*)(x + rowoff);
    const int base = m * 8 + 2 * g;
    float4 a0 = xr4[base],       b0 = xr4[base + 1];
    float4 a1 = xr4[base + 128], b1 = xr4[base + 129];
    float4 a2 = xr4[base + 256], b2 = xr4[base + 257];
    float4 a3 = xr4[base + 384], b3 = xr4[base + 385];

    // ---- phase A: q_n^jj table, jj=0..159 (per-thread fixed n)
    {
        int n = tid & 15;
        int idx = d * 16 + n;
        float a  = 1.f / (1.f + __expf(-alpha[idx]));
        float dl = 1.f / (1.f + __expf(-delta[idx]));
        float th = (1.f / (1.f + __expf(-theta[d]))) * (6.283185307179586f / 16.f);
        float phi = (float)(n + 1) * th;
        float radius = fminf(1.f - a * dl, 1.f);
        float lr = __logf(radius);
        for (int e = tid; e < 2560; e += 512) {
            int jj = e >> 4;                 // 0..159 (same n each iter)
            float rj = __expf((float)jj * lr);    // == reference decay
            float sn, cs; __sincosf((float)jj * phi, &sn, &cs);
            tr[jj * 17 + n] = rj * cs;
            ti[jj * 17 + n] = rj * sn;
        }
        if (tid < 16) {
            gprs[n] = gamma_r[idx] * 0.25f * a;
            gpis[n] = gamma_i[idx] * 0.25f * a;
        }
    }
    __syncthreads();

    // ---- phase B: kernel taps kappa[0..159]
    if (tid < 160) {
        float s = 0.f;
        #pragma unroll
        for (int n = 0; n < 16; ++n)
            s += gprs[n] * tr[tid * 17 + n] - gpis[n] * ti[tid * 17 + n];
        if (tid == 0) s += omega[d];
        kap[tid] = s;
    }
    __syncthreads();

    // ---- phase C: T_k A-fragments (overlay table region; reads only kap)
    _Float16* fragH = (_Float16*)smem;
    for (int s = tid; s < 640; s += 512) {
        int matk = s >> 7;                   // tap 0..4
        int sub = s & 127;
        int rt = sub >> 6, ll = sub & 63;
        int row = rt * 16 + (ll & 15);
        int kb = 8 * (ll >> 4);
        union { _Float16 h[8]; f16x8 v; } fv;
        #pragma unroll
        for (int j = 0; j < 8; ++j) {
            int lag = 32 * matk + row - kb - j;    // max 159, min -31
            fv.h[j] = (lag >= 0) ? (_Float16)kap[lag] : (_Float16)0.f;
        }
        *(f16x8*)&fragH[(matk * 128 + rt * 64 + ll) * 8] = fv.v;
    }
    __syncthreads();                     // frags visible; table dead

    // ================= per-wave independent section (no barriers) ========
    const f16x8* frag = (const f16x8*)smem;

    f16x8 xf[4];
    xf[0] = cvt8(a0, b0); xf[1] = cvt8(a1, b1);
    xf[2] = cvt8(a2, b2); xf[3] = cvt8(a3, b3);

    float4* or4 = (float4*)(out + rowoff);
    const f16x8 z8 = (f16x8)(_Float16)0.f;
    const int sl1 = (l & 48) | ((l - 1) & 15);
    const int sl2 = (l & 48) | ((l - 2) & 15);
    const int sl3 = (l & 48) | ((l - 3) & 15);
    const int sl4 = (l & 48) | ((l - 4) & 15);

    f16x8 p1 = z8, p2 = z8, p3 = z8, p4 = z8;   // rot_k(xf[tc-1])

    #pragma unroll
    for (int tc = 0; tc < 4; ++tc) {
        f16x8 xc = xf[tc];
        // rotations of this tile (also next tile's prev)
        f16x8 r1 = shfl8(xc, sl1);
        f16x8 r2 = shfl8(xc, sl2);
        f16x8 r3 = shfl8(xc, sl3);
        f16x8 r4 = shfl8(xc, sl4);

        f32x4 y0 = {0.f, 0.f, 0.f, 0.f}, y1 = {0.f, 0.f, 0.f, 0.f};
        y0 = __builtin_amdgcn_mfma_f32_16x16x32_f16(frag[l],      xc, y0, 0, 0, 0);
        y1 = __builtin_amdgcn_mfma_f32_16x16x32_f16(frag[64 + l], xc, y1, 0, 0, 0);

        f16x8 bf;
        bf = sel8(m >= 1, r1, p1);
        y0 = __builtin_amdgcn_mfma_f32_16x16x32_f16(frag[128 + l], bf, y0, 0, 0, 0);
        y1 = __builtin_amdgcn_mfma_f32_16x16x32_f16(frag[192 + l], bf, y1, 0, 0, 0);
        bf = sel8(m >= 2, r2, p2);
        y0 = __builtin_amdgcn_mfma_f32_16x16x32_f16(frag[256 + l], bf, y0, 0, 0, 0);
        y1 = __builtin_amdgcn_mfma_f32_16x16x32_f16(frag[320 + l], bf, y1, 0, 0, 0);
        bf = sel8(m >= 3, r3, p3);
        y0 = __builtin_amdgcn_mfma_f32_16x16x32_f16(frag[384 + l], bf, y0, 0, 0, 0);
        y1 = __builtin_amdgcn_mfma_f32_16x16x32_f16(frag[448 + l], bf, y1, 0, 0, 0);
        bf = sel8(m >= 4, r4, p4);
        y0 = __builtin_amdgcn_mfma_f32_16x16x32_f16(frag[512 + l], bf, y0, 0, 0, 0);
        y1 = __builtin_amdgcn_mfma_f32_16x16x32_f16(frag[576 + l], bf, y1, 0, 0, 0);

        // store this tile NOW (spreads the chip-wide write stream)
        float4 o0, o1;
        o0.x = y0[0]; o0.y = y0[1]; o0.z = y0[2]; o0.w = y0[3];
        o1.x = y1[0]; o1.y = y1[1]; o1.z = y1[2]; o1.w = y1[3];
        or4[(tc * 16 + m) * 8 + g]     = o0;
        or4[(tc * 16 + m) * 8 + 4 + g] = o1;

        p1 = r1; p2 = r2; p3 = r3; p4 = r4;
    }
}

extern "C" void kernel_launch(void* const* d_in, const int* in_sizes, int n_in,
                              void* d_out, int out_size, void* d_ws, size_t ws_size,
                              hipStream_t stream) {
    const float* x       = (const float*)d_in[0];
    const float* alpha   = (const float*)d_in[1];
    const float* delta   = (const float*)d_in[2];
    const float* theta   = (const float*)d_in[3];
    const float* gamma_r = (const float*)d_in[4];
    const float* gamma_i = (const float*)d_in[5];
    const float* omega   = (const float*)d_in[6];
    float* out = (float*)d_out;

    ema_fused<<<Dc, 512, 0, stream>>>(x, alpha, delta, theta,
                                      gamma_r, gamma_i, omega, out);
}